// Round 9
// baseline (617.995 us; speedup 1.0000x reference)
//
#include <hip/hip_runtime.h>

#define N_NODES 100000
#define N_EDGES 3200000
#define D 128
#define K 8

// |score32| below this => exact fp64 repair. fp32 score error sigma ~1e-5,
// so 2e-3 is ~200 sigma: no sign flip can survive unflagged.
#define TAU 2e-3f
#define WL_CAP 262144  // repair worklist capacity

#define CHUNK 256  // nodes per head_gemm block (4 subgroups of 64)
#define CCH   16   // output columns per wave (8 waves x 16 = 128)
#define GWAVES 8   // waves per head_gemm block (512 threads)
#define JH    32   // j-rows staged per pass (4 passes cover D=128)

// ---------------------------------------------------------------------------
// Phase 0: per-head compaction of masked node ids + per-node mask bitmap.
// Block-aggregated counter atomics (R7: cut per-address contention 4x,
// worth ~140 us).
// ---------------------------------------------------------------------------
__global__ __launch_bounds__(256)
void compact_kernel(const float* __restrict__ mask,
                    int* __restrict__ lists,
                    int* __restrict__ cnts,
                    unsigned char* __restrict__ mb)
{
    __shared__ int wcnt[4][K];
    __shared__ int wbase[4][K];

    const int n = blockIdx.x * 256 + threadIdx.x;
    const int lane = threadIdx.x & 63;
    const int wave = threadIdx.x >> 6;
    const bool valid = (n < N_NODES);

    unsigned long long ball[K];
    int bits8 = 0;
    #pragma unroll
    for (int k = 0; k < K; ++k) {
        const bool m = valid && (mask[(size_t)n * K + k] > 0.0f);
        bits8 |= m ? (1 << k) : 0;
        ball[k] = __ballot(m);
        if (lane == 0) wcnt[wave][k] = __popcll(ball[k]);
    }
    __syncthreads();

    if (threadIdx.x < K) {
        const int k = threadIdx.x;
        const int t0 = wcnt[0][k], t1 = wcnt[1][k], t2 = wcnt[2][k], t3 = wcnt[3][k];
        const int base = (t0 + t1 + t2 + t3)
                       ? atomicAdd(&cnts[k], t0 + t1 + t2 + t3) : 0;
        wbase[0][k] = base;
        wbase[1][k] = base + t0;
        wbase[2][k] = base + t0 + t1;
        wbase[3][k] = base + t0 + t1 + t2;
    }
    __syncthreads();

    #pragma unroll
    for (int k = 0; k < K; ++k) {
        if ((ball[k] >> lane) & 1ull) {
            const int pos = __popcll(ball[k] & ((1ull << lane) - 1ull));
            lists[(size_t)k * N_NODES + wbase[wave][k] + pos] = n;
        }
    }
    if (valid) mb[n] = (unsigned char)bits8;
}

// ---------------------------------------------------------------------------
// Phase 1 (fp32): for each compacted (node,head):
//   t32[n,k]    = relu(x[n] @ Ww_k) . Wm_k
//   base32[n,k] = x[n] . Wm_k
// The binding resource is the scalar-fetch path for W rows (R7/R8 both
// saturate it at ~1.2 TB/s device-wide). Block = 256 nodes x 1 head:
// each 64 B W-row s_load feeds 64 fmacs (4 subgroups of 64 nodes) ->
// 1 B/fmac; total W scalar traffic 100 MB -> ~83 us stream time, right at
// the 83 us fmac floor. K split into 4 passes of 32 j, xT[32][257] re-staged
// per pass (pad+1: staging writes and reads both conflict-free).
// LDS 50.3 KB -> 3 blocks/CU. launch_bounds(512,6) caps VGPR at 85
// (acc[4][16]=64 + ~16 live).
// Grid swizzle: the 8 heads of one node-chunk share bid%8 (same XCD).
// ---------------------------------------------------------------------------
__global__ __launch_bounds__(512, 6)
void head_gemm_kernel(const float* __restrict__ x,
                      const float* __restrict__ Ww,
                      const float* __restrict__ Wm,
                      const int* __restrict__ lists,
                      const int* __restrict__ cnts,
                      float* __restrict__ t32,
                      float* __restrict__ base32)
{
    __shared__ float xT[JH][CHUNK + 1];      // 32 x 257 = 32.9 KB
    __shared__ float redT[GWAVES][CHUNK];    // 8 KB
    __shared__ float redB[GWAVES][CHUNK];    // 8 KB
    __shared__ int   ids[CHUNK];             // 1 KB

    const int bid = blockIdx.x;
    const int k = (bid >> 3) & 7;
    const int c = ((bid >> 6) << 3) | (bid & 7);

    const int cnt = cnts[k];
    const int nbase = c * CHUNK;
    if (nbase >= cnt) return;            // block-uniform exit (before barriers)

    const int tid = threadIdx.x;
    const int lane = tid & 63;
    const int wave = __builtin_amdgcn_readfirstlane((int)(tid >> 6));
    const int* list = lists + (size_t)k * N_NODES;

    // node ids once into LDS (tail rows duplicated; writes guarded later)
    if (tid < CHUNK) {
        int idx = nbase + tid;
        if (idx >= cnt) idx = cnt - 1;
        ids[tid] = list[idx];
    }
    __syncthreads();

    const int c0 = wave * CCH;
    const float* Wk = Ww + (size_t)k * D * D + c0;

    float acc[4][CCH];
    #pragma unroll
    for (int s = 0; s < 4; ++s)
        #pragma unroll
        for (int cc = 0; cc < CCH; ++cc) acc[s][cc] = 0.0f;
    float bp[4] = {0.0f, 0.0f, 0.0f, 0.0f};

    const int jlane = tid & 31;          // j-offset within pass (staging)
    const int rbase = tid >> 5;          // row group 0..15

    #pragma unroll
    for (int p = 0; p < 4; ++p) {
        // stage 256 rows x 32 j-floats: 16 sweeps of 16 rows; 32 lanes read
        // 128 B contiguous per row (id uniform within the 32-lane row group)
        #pragma unroll
        for (int sw = 0; sw < 16; ++sw) {
            const int r = sw * 16 + rbase;
            const int id = ids[r];
            xT[jlane][r] = x[(size_t)id * D + p * JH + jlane];
        }
        __syncthreads();

        #pragma unroll 2
        for (int jl = 0; jl < JH; ++jl) {
            const float* wr = Wk + (p * JH + jl) * D;  // wave-uniform s_load
            const float xv0 = xT[jl][lane];
            const float xv1 = xT[jl][lane + 64];
            const float xv2 = xT[jl][lane + 128];
            const float xv3 = xT[jl][lane + 192];
            #pragma unroll
            for (int cc = 0; cc < CCH; ++cc) {
                const float wv = wr[cc];
                acc[0][cc] = fmaf(xv0, wv, acc[0][cc]);
                acc[1][cc] = fmaf(xv1, wv, acc[1][cc]);
                acc[2][cc] = fmaf(xv2, wv, acc[2][cc]);
                acc[3][cc] = fmaf(xv3, wv, acc[3][cc]);
            }
        }

        // base partial: this wave's j-columns [c0,c0+16) live in pass c0/32
        if ((c0 >> 5) == p) {
            const int jb = c0 & (JH - 1);
            #pragma unroll
            for (int cc = 0; cc < CCH; ++cc) {
                const float wm = Wm[k * D + c0 + cc];
                bp[0] = fmaf(xT[jb + cc][lane], wm, bp[0]);
                bp[1] = fmaf(xT[jb + cc][lane + 64], wm, bp[1]);
                bp[2] = fmaf(xT[jb + cc][lane + 128], wm, bp[2]);
                bp[3] = fmaf(xT[jb + cc][lane + 192], wm, bp[3]);
            }
        }
        __syncthreads();   // xT consumed; safe to restage next pass
    }

    // t partial (relu then dot with Wm over this wave's columns)
    float tp[4] = {0.0f, 0.0f, 0.0f, 0.0f};
    #pragma unroll
    for (int cc = 0; cc < CCH; ++cc) {
        const float wm = Wm[k * D + c0 + cc];
        tp[0] = fmaf(fmaxf(acc[0][cc], 0.0f), wm, tp[0]);
        tp[1] = fmaf(fmaxf(acc[1][cc], 0.0f), wm, tp[1]);
        tp[2] = fmaf(fmaxf(acc[2][cc], 0.0f), wm, tp[2]);
        tp[3] = fmaf(fmaxf(acc[3][cc], 0.0f), wm, tp[3]);
    }
    #pragma unroll
    for (int s = 0; s < 4; ++s) {
        redT[wave][s * 64 + lane] = tp[s];
        redB[wave][s * 64 + lane] = bp[s];
    }
    __syncthreads();

    if (wave < 4) {
        const int r = wave * 64 + lane;          // node-slot 0..255
        const int idx = nbase + r;
        if (idx < cnt) {
            const int id = ids[r];
            float ts = 0.0f, bs = 0.0f;
            #pragma unroll
            for (int wv = 0; wv < GWAVES; ++wv) {
                ts += redT[wv][r];
                bs += redB[wv][r];
            }
            t32[(size_t)id * K + k]    = ts;
            base32[(size_t)id * K + k] = bs;
        }
    }
}

// ---------------------------------------------------------------------------
// Phase 2 (fp32): agg32[dst,k] += t32[src,k]. Lane = (edge, head): groups of
// 8 lanes cover one edge's 8 heads, so their atomics hit 8 consecutive
// floats (one 32 B sector -> hardware-merged; R5 WRITE_SIZE evidence).
// Gated by t!=0 (src masked) AND mb[dst] bit (agg dead if dst unmasked).
// ---------------------------------------------------------------------------
__global__ __launch_bounds__(256)
void scatter_kernel(const int* __restrict__ ei,
                    const unsigned char* __restrict__ mb,
                    const float* __restrict__ t32,
                    float* __restrict__ agg32)
{
    const long long tid = (long long)blockIdx.x * 256 + threadIdx.x;
    if (tid >= (long long)N_EDGES * K) return;
    const int k = (int)(tid & (K - 1));
    const long long e = tid >> 3;
    const int d = ei[(long long)N_EDGES + e];   // broadcast within 8-lane group
    const unsigned md = mb[d];
    if (!((md >> k) & 1)) return;
    const int s = ei[e];
    const float v = t32[(size_t)s * K + k];     // 32 B coalesced per group
    if (v != 0.0f) atomicAdd(&agg32[(size_t)d * K + k], v);
}

// ---------------------------------------------------------------------------
// Phase 3: tentative combine + flag near-zero scores for exact repair.
// head bool = (mask>0) && (score>0); output = first <=2 true heads (lax.top_k
// on all-equal norms tie-breaks by lowest index).
// ---------------------------------------------------------------------------
__global__ __launch_bounds__(256)
void combine_flag_kernel(const unsigned char* __restrict__ mb,
                         const float* __restrict__ base32,
                         const float* __restrict__ agg32,
                         float* __restrict__ out,
                         unsigned char* __restrict__ flag8)
{
    const int n = blockIdx.x * 256 + threadIdx.x;
    if (n >= N_NODES) return;
    const unsigned m8 = mb[n];
    float o[K];
    int cnt = 0, fl = 0;
    #pragma unroll
    for (int k = 0; k < K; ++k) {
        const float s = base32[(size_t)n * K + k] + agg32[(size_t)n * K + k];
        const bool masked = (m8 >> k) & 1;
        const bool hm = masked && (s > 0.0f);
        if (masked && fabsf(s) < TAU) fl |= (1 << k);
        o[k] = (hm && cnt < 2) ? 1.0f : 0.0f;
        cnt += hm ? 1 : 0;
    }
    float4* op = (float4*)(out + (size_t)n * K);
    op[0] = make_float4(o[0], o[1], o[2], o[3]);
    op[1] = make_float4(o[4], o[5], o[6], o[7]);
    flag8[n] = (unsigned char)fl;
}

// ---------------------------------------------------------------------------
// Repair A: edges into flagged (dst,k) with masked src -> worklist.
// ---------------------------------------------------------------------------
__global__ __launch_bounds__(256)
void edge_flag_kernel(const int* __restrict__ ei,
                      const unsigned char* __restrict__ mb,
                      const unsigned char* __restrict__ flag8,
                      int2* __restrict__ wl,
                      int* __restrict__ wlcnt)
{
    const int e = blockIdx.x * 256 + threadIdx.x;
    if (e >= N_EDGES) return;
    const int d = ei[(long long)N_EDGES + e];
    unsigned f = flag8[d];
    if (!f) return;
    const int s = ei[e];
    f &= mb[s];
    while (f) {
        const int k = __ffs(f) - 1;
        f &= f - 1;
        const int idx = atomicAdd(wlcnt, 1);
        if (idx < WL_CAP) wl[idx] = make_int2(s | (k << 20), d);
    }
}

// ---------------------------------------------------------------------------
// Repair B: one wave per worklist entry: exact fp64 t, atomic into score64.
// ---------------------------------------------------------------------------
__global__ __launch_bounds__(256)
void repair_t_kernel(const float* __restrict__ x,
                     const float* __restrict__ Ww,
                     const float* __restrict__ Wm,
                     const int2* __restrict__ wl,
                     const int* __restrict__ wlcnt,
                     double* __restrict__ score64)
{
    const int lane = threadIdx.x & 63;
    const int waveId = blockIdx.x * 4 + (threadIdx.x >> 6);
    const int nWaves = gridDim.x * 4;
    int cnt = *wlcnt;
    if (cnt > WL_CAP) cnt = WL_CAP;
    for (int w = waveId; w < cnt; w += nWaves) {
        const int2 ent = wl[w];
        const int s = __builtin_amdgcn_readfirstlane(ent.x & 0xFFFFF);
        const int k = __builtin_amdgcn_readfirstlane(ent.x >> 20);
        const int d = ent.y;
        const float* xr = x + (size_t)s * D;
        const float* Wk = Ww + (size_t)k * D * D;
        double c0 = 0.0, c1 = 0.0;
        for (int j = 0; j < D; ++j) {
            const double xd = (double)xr[j];
            c0 = fma(xd, (double)Wk[j * D + lane], c0);
            c1 = fma(xd, (double)Wk[j * D + lane + 64], c1);
        }
        double ts = fmax(c0, 0.0) * (double)Wm[k * D + lane]
                  + fmax(c1, 0.0) * (double)Wm[k * D + lane + 64];
        #pragma unroll
        for (int off = 32; off > 0; off >>= 1) ts += __shfl_xor(ts, off);
        if (lane == 0) atomicAdd(&score64[(size_t)d * K + k], ts);
    }
}

// ---------------------------------------------------------------------------
// Repair C: rewrite output rows of flagged nodes using exact scores.
// ---------------------------------------------------------------------------
__global__ __launch_bounds__(256)
void repair_combine_kernel(const float* __restrict__ x,
                           const unsigned char* __restrict__ mb,
                           const float* __restrict__ Wm,
                           const float* __restrict__ base32,
                           const float* __restrict__ agg32,
                           const double* __restrict__ score64,
                           const unsigned char* __restrict__ flag8,
                           float* __restrict__ out)
{
    const int n = blockIdx.x * 256 + threadIdx.x;
    if (n >= N_NODES) return;
    const unsigned f = flag8[n];
    if (!f) return;
    const unsigned m8 = mb[n];
    float o[K];
    int cnt = 0;
    #pragma unroll
    for (int k = 0; k < K; ++k) {
        bool hm;
        if ((f >> k) & 1) {
            double b = 0.0;
            for (int j = 0; j < D; ++j)
                b = fma((double)x[(size_t)n * D + j], (double)Wm[k * D + j], b);
            hm = (b + score64[(size_t)n * K + k]) > 0.0;
        } else {
            hm = ((m8 >> k) & 1) &&
                 ((base32[(size_t)n * K + k] + agg32[(size_t)n * K + k]) > 0.0f);
        }
        o[k] = (hm && cnt < 2) ? 1.0f : 0.0f;
        cnt += hm ? 1 : 0;
    }
    float4* op = (float4*)(out + (size_t)n * K);
    op[0] = make_float4(o[0], o[1], o[2], o[3]);
    op[1] = make_float4(o[4], o[5], o[6], o[7]);
}

extern "C" void kernel_launch(void* const* d_in, const int* in_sizes, int n_in,
                              void* d_out, int out_size, void* d_ws, size_t ws_size,
                              hipStream_t stream)
{
    const float* x    = (const float*)d_in[0];
    const int*   ei   = (const int*)d_in[1];   // edge_index [2, E] int32
    const float* mask = (const float*)d_in[2]; // [N, K]
    const float* Ww   = (const float*)d_in[3]; // [K, D, D]
    const float* Wm   = (const float*)d_in[4]; // [K, D, 1]
    float* out = (float*)d_out;                // [N, K] float32

    // workspace layout:
    //   [0, 3.2M)            t32      f32[N*K]
    //   [3.2M, 6.4M)         agg32    f32[N*K]
    //   [6.4M, 12.8M)        s64      f64[N*K]  (early: lists int[K][N], 3.2M)
    //   [12.8M, +100000)     flag8    u8[N]
    //   [12,900,000, +32)    cnts     int[8]
    //   [12,900,032, +4+pad) wlcnt    int
    //   [12,900,040, +2M)    wl       int2[WL_CAP]
    //   [14,997,192, +3.2M)  base32   f32[N*K]
    //   [18,197,192, +100000) mb      u8[N]      (end ~18.3 MB)
    char* w = (char*)d_ws;
    float*         t32    = (float*)w;
    float*         agg32  = (float*)(w + 3200000);
    double*        s64    = (double*)(w + 6400000);
    int*           lists  = (int*)(w + 6400000);       // overlays s64 (dead then)
    unsigned char* flag8  = (unsigned char*)(w + 12800000);
    int*           cnts   = (int*)(w + 12900000);
    int*           wlcnt  = (int*)(w + 12900032);
    int2*          wl     = (int2*)(w + 12900040);
    float*         b32    = (float*)(w + 12900040 + (size_t)WL_CAP * 8);
    unsigned char* mb     = (unsigned char*)(w + 12900040 + (size_t)WL_CAP * 8 + 3200000);

    // zero t32|agg32 and flag8|cnts|wlcnt (s64 zeroed later, after gemm)
    hipMemsetAsync(w, 0, 6400000, stream);
    hipMemsetAsync(w + 12800000, 0, 100040, stream);

    compact_kernel<<<(N_NODES + 255) / 256, 256, 0, stream>>>(mask, lists, cnts, mb);

    // grid: chunks padded to x8 so bid = c0*64 + h*8 + clo covers all (c,h)
    const int nchunks = (N_NODES + CHUNK - 1) / CHUNK;          // 391
    const int nc8 = (nchunks + 7) & ~7;                          // 392
    head_gemm_kernel<<<nc8 * K, 512, 0, stream>>>(x, Ww, Wm, lists, cnts, t32, b32);

    const long long nek = (long long)N_EDGES * K;
    scatter_kernel<<<(int)((nek + 255) / 256), 256, 0, stream>>>(ei, mb, t32, agg32);

    combine_flag_kernel<<<(N_NODES + 255) / 256, 256, 0, stream>>>(
        mb, b32, agg32, out, flag8);

    // lists dead now; zero s64 for exact re-accumulation
    hipMemsetAsync(s64, 0, 6400000, stream);

    edge_flag_kernel<<<(N_EDGES + 255) / 256, 256, 0, stream>>>(
        ei, mb, flag8, wl, wlcnt);

    repair_t_kernel<<<512, 256, 0, stream>>>(x, Ww, Wm, wl, wlcnt, s64);

    repair_combine_kernel<<<(N_NODES + 255) / 256, 256, 0, stream>>>(
        x, mb, Wm, b32, agg32, s64, flag8, out);
}

// Round 10
// 526.664 us; speedup vs baseline: 1.1734x; 1.1734x over previous
//
#include <hip/hip_runtime.h>

#define N_NODES 100000
#define N_EDGES 3200000
#define D 128
#define K 8

// |score32| below this => exact fp64 repair. fp32 score error sigma ~1e-5,
// so 2e-3 is ~200 sigma: no sign flip can survive unflagged.
#define TAU 2e-3f
#define WL_CAP 262144  // repair worklist capacity

#define CHUNK 256  // nodes per head_gemm block (4 subgroups of 64)
#define CCH   16   // output columns per wave (8 waves x 16 = 128)
#define GWAVES 8   // waves per head_gemm block (512 threads)
#define JH    32   // j-rows staged per pass (4 passes cover D=128)

// ---------------------------------------------------------------------------
// Phase 0: per-head compaction of masked node ids + per-node mask bitmap.
// Block-aggregated counter atomics (R7: cut per-address contention 4x,
// worth ~140 us).
// ---------------------------------------------------------------------------
__global__ __launch_bounds__(256)
void compact_kernel(const float* __restrict__ mask,
                    int* __restrict__ lists,
                    int* __restrict__ cnts,
                    unsigned char* __restrict__ mb)
{
    __shared__ int wcnt[4][K];
    __shared__ int wbase[4][K];

    const int n = blockIdx.x * 256 + threadIdx.x;
    const int lane = threadIdx.x & 63;
    const int wave = threadIdx.x >> 6;
    const bool valid = (n < N_NODES);

    unsigned long long ball[K];
    int bits8 = 0;
    #pragma unroll
    for (int k = 0; k < K; ++k) {
        const bool m = valid && (mask[(size_t)n * K + k] > 0.0f);
        bits8 |= m ? (1 << k) : 0;
        ball[k] = __ballot(m);
        if (lane == 0) wcnt[wave][k] = __popcll(ball[k]);
    }
    __syncthreads();

    if (threadIdx.x < K) {
        const int k = threadIdx.x;
        const int t0 = wcnt[0][k], t1 = wcnt[1][k], t2 = wcnt[2][k], t3 = wcnt[3][k];
        const int base = (t0 + t1 + t2 + t3)
                       ? atomicAdd(&cnts[k], t0 + t1 + t2 + t3) : 0;
        wbase[0][k] = base;
        wbase[1][k] = base + t0;
        wbase[2][k] = base + t0 + t1;
        wbase[3][k] = base + t0 + t1 + t2;
    }
    __syncthreads();

    #pragma unroll
    for (int k = 0; k < K; ++k) {
        if ((ball[k] >> lane) & 1ull) {
            const int pos = __popcll(ball[k] & ((1ull << lane) - 1ull));
            lists[(size_t)k * N_NODES + wbase[wave][k] + pos] = n;
        }
    }
    if (valid) mb[n] = (unsigned char)bits8;
}

// ---------------------------------------------------------------------------
// Phase 1 (fp32): for each compacted (node,head):
//   t32[n,k]    = relu(x[n] @ Ww_k) . Wm_k
//   base32[n,k] = x[n] . Wm_k
// Binding resource: scalar-fetch path for W rows (R7/R8 saturate it at
// ~1.2 TB/s device-wide). Block = 256 nodes x 1 head: each 64 B W-row
// s_load feeds 64 fmacs (4 subgroups of 64 nodes) -> 1 B/fmac; W scalar
// traffic 100 MB -> ~83 us stream, at the 83 us fmac floor.
// R9 LESSON: launch_bounds(512,6) squeezed VGPRs below the 64-float acc
// footprint -> scratch spills (WRITE_SIZE 13->116 MB, 250 us). (512,4)
// gives ~128 VGPRs: acc[4][16]=64 + ~30 live fits spill-free. 2 blocks/CU
// (R7: wave count is not binding).
// K split into 4 passes of 32 j, xT[32][257] re-staged per pass.
// Grid swizzle: the 8 heads of one node-chunk share bid%8 (same XCD).
// ---------------------------------------------------------------------------
__global__ __launch_bounds__(512, 4)
void head_gemm_kernel(const float* __restrict__ x,
                      const float* __restrict__ Ww,
                      const float* __restrict__ Wm,
                      const int* __restrict__ lists,
                      const int* __restrict__ cnts,
                      float* __restrict__ t32,
                      float* __restrict__ base32)
{
    __shared__ float xT[JH][CHUNK + 1];      // 32 x 257 = 32.9 KB
    __shared__ float redT[GWAVES][CHUNK];    // 8 KB
    __shared__ float redB[GWAVES][CHUNK];    // 8 KB
    __shared__ int   ids[CHUNK];             // 1 KB

    const int bid = blockIdx.x;
    const int k = (bid >> 3) & 7;
    const int c = ((bid >> 6) << 3) | (bid & 7);

    const int cnt = cnts[k];
    const int nbase = c * CHUNK;
    if (nbase >= cnt) return;            // block-uniform exit (before barriers)

    const int tid = threadIdx.x;
    const int lane = tid & 63;
    const int wave = __builtin_amdgcn_readfirstlane((int)(tid >> 6));
    const int* list = lists + (size_t)k * N_NODES;

    // node ids once into LDS (tail rows duplicated; writes guarded later)
    if (tid < CHUNK) {
        int idx = nbase + tid;
        if (idx >= cnt) idx = cnt - 1;
        ids[tid] = list[idx];
    }
    __syncthreads();

    const int c0 = wave * CCH;
    const float* Wk = Ww + (size_t)k * D * D + c0;

    float acc[4][CCH];
    #pragma unroll
    for (int s = 0; s < 4; ++s)
        #pragma unroll
        for (int cc = 0; cc < CCH; ++cc) acc[s][cc] = 0.0f;
    float bp[4] = {0.0f, 0.0f, 0.0f, 0.0f};

    const int jlane = tid & 31;          // j-offset within pass (staging)
    const int rbase = tid >> 5;          // row group 0..15

    #pragma unroll
    for (int p = 0; p < 4; ++p) {
        // stage 256 rows x 32 j-floats: 16 sweeps of 16 rows; 32 lanes read
        // 128 B contiguous per row (id uniform within the 32-lane row group)
        #pragma unroll
        for (int sw = 0; sw < 16; ++sw) {
            const int r = sw * 16 + rbase;
            const int id = ids[r];
            xT[jlane][r] = x[(size_t)id * D + p * JH + jlane];
        }
        __syncthreads();

        #pragma unroll 2
        for (int jl = 0; jl < JH; ++jl) {
            const float* wr = Wk + (p * JH + jl) * D;  // wave-uniform s_load
            const float xv0 = xT[jl][lane];
            const float xv1 = xT[jl][lane + 64];
            const float xv2 = xT[jl][lane + 128];
            const float xv3 = xT[jl][lane + 192];
            #pragma unroll
            for (int cc = 0; cc < CCH; ++cc) {
                const float wv = wr[cc];
                acc[0][cc] = fmaf(xv0, wv, acc[0][cc]);
                acc[1][cc] = fmaf(xv1, wv, acc[1][cc]);
                acc[2][cc] = fmaf(xv2, wv, acc[2][cc]);
                acc[3][cc] = fmaf(xv3, wv, acc[3][cc]);
            }
        }

        // base partial: this wave's j-columns [c0,c0+16) live in pass c0/32
        if ((c0 >> 5) == p) {
            const int jb = c0 & (JH - 1);
            #pragma unroll
            for (int cc = 0; cc < CCH; ++cc) {
                const float wm = Wm[k * D + c0 + cc];
                bp[0] = fmaf(xT[jb + cc][lane], wm, bp[0]);
                bp[1] = fmaf(xT[jb + cc][lane + 64], wm, bp[1]);
                bp[2] = fmaf(xT[jb + cc][lane + 128], wm, bp[2]);
                bp[3] = fmaf(xT[jb + cc][lane + 192], wm, bp[3]);
            }
        }
        __syncthreads();   // xT consumed; safe to restage next pass
    }

    // t partial (relu then dot with Wm over this wave's columns)
    float tp[4] = {0.0f, 0.0f, 0.0f, 0.0f};
    #pragma unroll
    for (int cc = 0; cc < CCH; ++cc) {
        const float wm = Wm[k * D + c0 + cc];
        tp[0] = fmaf(fmaxf(acc[0][cc], 0.0f), wm, tp[0]);
        tp[1] = fmaf(fmaxf(acc[1][cc], 0.0f), wm, tp[1]);
        tp[2] = fmaf(fmaxf(acc[2][cc], 0.0f), wm, tp[2]);
        tp[3] = fmaf(fmaxf(acc[3][cc], 0.0f), wm, tp[3]);
    }
    #pragma unroll
    for (int s = 0; s < 4; ++s) {
        redT[wave][s * 64 + lane] = tp[s];
        redB[wave][s * 64 + lane] = bp[s];
    }
    __syncthreads();

    if (wave < 4) {
        const int r = wave * 64 + lane;          // node-slot 0..255
        const int idx = nbase + r;
        if (idx < cnt) {
            const int id = ids[r];
            float ts = 0.0f, bs = 0.0f;
            #pragma unroll
            for (int wv = 0; wv < GWAVES; ++wv) {
                ts += redT[wv][r];
                bs += redB[wv][r];
            }
            t32[(size_t)id * K + k]    = ts;
            base32[(size_t)id * K + k] = bs;
        }
    }
}

// ---------------------------------------------------------------------------
// Phase 2 (fp32): agg32[dst,k] += t32[src,k]. Lane = (edge, head): groups of
// 8 lanes cover one edge's 8 heads, so their atomics hit 8 consecutive
// floats (one 32 B sector -> hardware-merged; R5 WRITE_SIZE evidence).
// Gated by t!=0 (src masked) AND mb[dst] bit (agg dead if dst unmasked).
// ---------------------------------------------------------------------------
__global__ __launch_bounds__(256)
void scatter_kernel(const int* __restrict__ ei,
                    const unsigned char* __restrict__ mb,
                    const float* __restrict__ t32,
                    float* __restrict__ agg32)
{
    const long long tid = (long long)blockIdx.x * 256 + threadIdx.x;
    if (tid >= (long long)N_EDGES * K) return;
    const int k = (int)(tid & (K - 1));
    const long long e = tid >> 3;
    const int d = ei[(long long)N_EDGES + e];   // broadcast within 8-lane group
    const unsigned md = mb[d];
    if (!((md >> k) & 1)) return;
    const int s = ei[e];
    const float v = t32[(size_t)s * K + k];     // 32 B coalesced per group
    if (v != 0.0f) atomicAdd(&agg32[(size_t)d * K + k], v);
}

// ---------------------------------------------------------------------------
// Phase 3: tentative combine + flag near-zero scores for exact repair.
// head bool = (mask>0) && (score>0); output = first <=2 true heads (lax.top_k
// on all-equal norms tie-breaks by lowest index).
// ---------------------------------------------------------------------------
__global__ __launch_bounds__(256)
void combine_flag_kernel(const unsigned char* __restrict__ mb,
                         const float* __restrict__ base32,
                         const float* __restrict__ agg32,
                         float* __restrict__ out,
                         unsigned char* __restrict__ flag8)
{
    const int n = blockIdx.x * 256 + threadIdx.x;
    if (n >= N_NODES) return;
    const unsigned m8 = mb[n];
    float o[K];
    int cnt = 0, fl = 0;
    #pragma unroll
    for (int k = 0; k < K; ++k) {
        const float s = base32[(size_t)n * K + k] + agg32[(size_t)n * K + k];
        const bool masked = (m8 >> k) & 1;
        const bool hm = masked && (s > 0.0f);
        if (masked && fabsf(s) < TAU) fl |= (1 << k);
        o[k] = (hm && cnt < 2) ? 1.0f : 0.0f;
        cnt += hm ? 1 : 0;
    }
    float4* op = (float4*)(out + (size_t)n * K);
    op[0] = make_float4(o[0], o[1], o[2], o[3]);
    op[1] = make_float4(o[4], o[5], o[6], o[7]);
    flag8[n] = (unsigned char)fl;
}

// ---------------------------------------------------------------------------
// Repair A: edges into flagged (dst,k) with masked src -> worklist.
// ---------------------------------------------------------------------------
__global__ __launch_bounds__(256)
void edge_flag_kernel(const int* __restrict__ ei,
                      const unsigned char* __restrict__ mb,
                      const unsigned char* __restrict__ flag8,
                      int2* __restrict__ wl,
                      int* __restrict__ wlcnt)
{
    const int e = blockIdx.x * 256 + threadIdx.x;
    if (e >= N_EDGES) return;
    const int d = ei[(long long)N_EDGES + e];
    unsigned f = flag8[d];
    if (!f) return;
    const int s = ei[e];
    f &= mb[s];
    while (f) {
        const int k = __ffs(f) - 1;
        f &= f - 1;
        const int idx = atomicAdd(wlcnt, 1);
        if (idx < WL_CAP) wl[idx] = make_int2(s | (k << 20), d);
    }
}

// ---------------------------------------------------------------------------
// Repair B: one wave per worklist entry: exact fp64 t, atomic into score64.
// ---------------------------------------------------------------------------
__global__ __launch_bounds__(256)
void repair_t_kernel(const float* __restrict__ x,
                     const float* __restrict__ Ww,
                     const float* __restrict__ Wm,
                     const int2* __restrict__ wl,
                     const int* __restrict__ wlcnt,
                     double* __restrict__ score64)
{
    const int lane = threadIdx.x & 63;
    const int waveId = blockIdx.x * 4 + (threadIdx.x >> 6);
    const int nWaves = gridDim.x * 4;
    int cnt = *wlcnt;
    if (cnt > WL_CAP) cnt = WL_CAP;
    for (int w = waveId; w < cnt; w += nWaves) {
        const int2 ent = wl[w];
        const int s = __builtin_amdgcn_readfirstlane(ent.x & 0xFFFFF);
        const int k = __builtin_amdgcn_readfirstlane(ent.x >> 20);
        const int d = ent.y;
        const float* xr = x + (size_t)s * D;
        const float* Wk = Ww + (size_t)k * D * D;
        double c0 = 0.0, c1 = 0.0;
        for (int j = 0; j < D; ++j) {
            const double xd = (double)xr[j];
            c0 = fma(xd, (double)Wk[j * D + lane], c0);
            c1 = fma(xd, (double)Wk[j * D + lane + 64], c1);
        }
        double ts = fmax(c0, 0.0) * (double)Wm[k * D + lane]
                  + fmax(c1, 0.0) * (double)Wm[k * D + lane + 64];
        #pragma unroll
        for (int off = 32; off > 0; off >>= 1) ts += __shfl_xor(ts, off);
        if (lane == 0) atomicAdd(&score64[(size_t)d * K + k], ts);
    }
}

// ---------------------------------------------------------------------------
// Repair C: rewrite output rows of flagged nodes using exact scores.
// ---------------------------------------------------------------------------
__global__ __launch_bounds__(256)
void repair_combine_kernel(const float* __restrict__ x,
                           const unsigned char* __restrict__ mb,
                           const float* __restrict__ Wm,
                           const float* __restrict__ base32,
                           const float* __restrict__ agg32,
                           const double* __restrict__ score64,
                           const unsigned char* __restrict__ flag8,
                           float* __restrict__ out)
{
    const int n = blockIdx.x * 256 + threadIdx.x;
    if (n >= N_NODES) return;
    const unsigned f = flag8[n];
    if (!f) return;
    const unsigned m8 = mb[n];
    float o[K];
    int cnt = 0;
    #pragma unroll
    for (int k = 0; k < K; ++k) {
        bool hm;
        if ((f >> k) & 1) {
            double b = 0.0;
            for (int j = 0; j < D; ++j)
                b = fma((double)x[(size_t)n * D + j], (double)Wm[k * D + j], b);
            hm = (b + score64[(size_t)n * K + k]) > 0.0;
        } else {
            hm = ((m8 >> k) & 1) &&
                 ((base32[(size_t)n * K + k] + agg32[(size_t)n * K + k]) > 0.0f);
        }
        o[k] = (hm && cnt < 2) ? 1.0f : 0.0f;
        cnt += hm ? 1 : 0;
    }
    float4* op = (float4*)(out + (size_t)n * K);
    op[0] = make_float4(o[0], o[1], o[2], o[3]);
    op[1] = make_float4(o[4], o[5], o[6], o[7]);
}

extern "C" void kernel_launch(void* const* d_in, const int* in_sizes, int n_in,
                              void* d_out, int out_size, void* d_ws, size_t ws_size,
                              hipStream_t stream)
{
    const float* x    = (const float*)d_in[0];
    const int*   ei   = (const int*)d_in[1];   // edge_index [2, E] int32
    const float* mask = (const float*)d_in[2]; // [N, K]
    const float* Ww   = (const float*)d_in[3]; // [K, D, D]
    const float* Wm   = (const float*)d_in[4]; // [K, D, 1]
    float* out = (float*)d_out;                // [N, K] float32

    // workspace layout:
    //   [0, 3.2M)            t32      f32[N*K]
    //   [3.2M, 6.4M)         agg32    f32[N*K]
    //   [6.4M, 12.8M)        s64      f64[N*K]  (early: lists int[K][N], 3.2M)
    //   [12.8M, +100000)     flag8    u8[N]
    //   [12,900,000, +32)    cnts     int[8]
    //   [12,900,032, +4+pad) wlcnt    int
    //   [12,900,040, +2M)    wl       int2[WL_CAP]
    //   [14,997,192, +3.2M)  base32   f32[N*K]
    //   [18,197,192, +100000) mb      u8[N]      (end ~18.3 MB)
    char* w = (char*)d_ws;
    float*         t32    = (float*)w;
    float*         agg32  = (float*)(w + 3200000);
    double*        s64    = (double*)(w + 6400000);
    int*           lists  = (int*)(w + 6400000);       // overlays s64 (dead then)
    unsigned char* flag8  = (unsigned char*)(w + 12800000);
    int*           cnts   = (int*)(w + 12900000);
    int*           wlcnt  = (int*)(w + 12900032);
    int2*          wl     = (int2*)(w + 12900040);
    float*         b32    = (float*)(w + 12900040 + (size_t)WL_CAP * 8);
    unsigned char* mb     = (unsigned char*)(w + 12900040 + (size_t)WL_CAP * 8 + 3200000);

    // zero t32|agg32 and flag8|cnts|wlcnt (s64 zeroed later, after gemm)
    hipMemsetAsync(w, 0, 6400000, stream);
    hipMemsetAsync(w + 12800000, 0, 100040, stream);

    compact_kernel<<<(N_NODES + 255) / 256, 256, 0, stream>>>(mask, lists, cnts, mb);

    // grid: chunks padded to x8 so bid = c0*64 + h*8 + clo covers all (c,h)
    const int nchunks = (N_NODES + CHUNK - 1) / CHUNK;          // 391
    const int nc8 = (nchunks + 7) & ~7;                          // 392
    head_gemm_kernel<<<nc8 * K, 512, 0, stream>>>(x, Ww, Wm, lists, cnts, t32, b32);

    const long long nek = (long long)N_EDGES * K;
    scatter_kernel<<<(int)((nek + 255) / 256), 256, 0, stream>>>(ei, mb, t32, agg32);

    combine_flag_kernel<<<(N_NODES + 255) / 256, 256, 0, stream>>>(
        mb, b32, agg32, out, flag8);

    // lists dead now; zero s64 for exact re-accumulation
    hipMemsetAsync(s64, 0, 6400000, stream);

    edge_flag_kernel<<<(N_EDGES + 255) / 256, 256, 0, stream>>>(
        ei, mb, flag8, wl, wlcnt);

    repair_t_kernel<<<512, 256, 0, stream>>>(x, Ww, Wm, wl, wlcnt, s64);

    repair_combine_kernel<<<(N_NODES + 255) / 256, 256, 0, stream>>>(
        x, mb, Wm, b32, agg32, s64, flag8, out);
}

// Round 11
// 503.603 us; speedup vs baseline: 1.2271x; 1.0458x over previous
//
#include <hip/hip_runtime.h>

#define N_NODES 100000
#define N_EDGES 3200000
#define D 128
#define K 8

// |score32| below this => exact fp64 repair. fp32 score error sigma ~1e-5,
// so 2e-3 is ~200 sigma: no sign flip can survive unflagged.
#define TAU 2e-3f
#define WL_CAP 262144  // repair worklist capacity

#define CHUNK 128  // nodes per head_gemm block (2 subgroups of 64)
#define CCH   16   // output columns per wave (8 waves x 16 = 128)
#define GWAVES 8   // waves per head_gemm block (512 threads)
#define JH    64   // j-rows staged per pass (2 passes cover D=128)

// ---------------------------------------------------------------------------
// Phase 0: per-head compaction of masked node ids + per-node mask bitmap.
// Block-aggregated counter atomics (R7: 4x less per-address contention).
// ---------------------------------------------------------------------------
__global__ __launch_bounds__(256)
void compact_kernel(const float* __restrict__ mask,
                    int* __restrict__ lists,
                    int* __restrict__ cnts,
                    unsigned char* __restrict__ mb)
{
    __shared__ int wcnt[4][K];
    __shared__ int wbase[4][K];

    const int n = blockIdx.x * 256 + threadIdx.x;
    const int lane = threadIdx.x & 63;
    const int wave = threadIdx.x >> 6;
    const bool valid = (n < N_NODES);

    unsigned long long ball[K];
    int bits8 = 0;
    #pragma unroll
    for (int k = 0; k < K; ++k) {
        const bool m = valid && (mask[(size_t)n * K + k] > 0.0f);
        bits8 |= m ? (1 << k) : 0;
        ball[k] = __ballot(m);
        if (lane == 0) wcnt[wave][k] = __popcll(ball[k]);
    }
    __syncthreads();

    if (threadIdx.x < K) {
        const int k = threadIdx.x;
        const int t0 = wcnt[0][k], t1 = wcnt[1][k], t2 = wcnt[2][k], t3 = wcnt[3][k];
        const int base = (t0 + t1 + t2 + t3)
                       ? atomicAdd(&cnts[k], t0 + t1 + t2 + t3) : 0;
        wbase[0][k] = base;
        wbase[1][k] = base + t0;
        wbase[2][k] = base + t0 + t1;
        wbase[3][k] = base + t0 + t1 + t2;
    }
    __syncthreads();

    #pragma unroll
    for (int k = 0; k < K; ++k) {
        if ((ball[k] >> lane) & 1ull) {
            const int pos = __popcll(ball[k] & ((1ull << lane) - 1ull));
            lists[(size_t)k * N_NODES + wbase[wave][k] + pos] = n;
        }
    }
    if (valid) mb[n] = (unsigned char)bits8;
}

// ---------------------------------------------------------------------------
// Phase 1 (fp32): for each compacted (node,head):
//   t32[n,k]    = relu(x[n] @ Ww_k) . Wm_k
//   base32[n,k] = x[n] . Wm_k
// R10 post-mortem: occupancy is REGISTER-bound (56 arch + 64 acc ~= 128/wave
// cap -> 2 blocks/CU), and the residual stall is pass-boundary staging with
// all resident waves barriered together. Fix: CHUNK=128 + JH=64 (2 passes)
// -> acc[2][16] = 32 regs, launch_bounds(512,6) caps total at 85 ->
// 3 blocks/CU (LDS 41.5 KB) = 24 waves, staging overlaps across blocks;
// half the barriers; float4 staging (16 B/lane). W traffic 401 MB: proven
// non-binding (R8 vs R10: halving it left time unchanged).
// LDS bank math: xT[j][r] bank=(j+r)%32 (129%32=1) -> both staging writes
// and xv reads are <=2-way aliased = free (m136).
// Grid swizzle: the 8 heads of one node-chunk share bid%8 (same XCD).
// ---------------------------------------------------------------------------
__global__ __launch_bounds__(512, 6)
void head_gemm_kernel(const float* __restrict__ x,
                      const float* __restrict__ Ww,
                      const float* __restrict__ Wm,
                      const int* __restrict__ lists,
                      const int* __restrict__ cnts,
                      float* __restrict__ t32,
                      float* __restrict__ base32)
{
    __shared__ float xT[JH][CHUNK + 1];      // 64 x 129 = 33.0 KB
    __shared__ float redT[GWAVES][CHUNK];    // 4 KB
    __shared__ float redB[GWAVES][CHUNK];    // 4 KB
    __shared__ int   ids[CHUNK];             // 0.5 KB

    const int bid = blockIdx.x;
    const int k = (bid >> 3) & 7;
    const int c = ((bid >> 6) << 3) | (bid & 7);

    const int cnt = cnts[k];
    const int nbase = c * CHUNK;
    if (nbase >= cnt) return;            // block-uniform exit (before barriers)

    const int tid = threadIdx.x;
    const int lane = tid & 63;
    const int wave = __builtin_amdgcn_readfirstlane((int)(tid >> 6));
    const int* list = lists + (size_t)k * N_NODES;

    // node ids once into LDS (tail rows duplicated; writes guarded later)
    if (tid < CHUNK) {
        int idx = nbase + tid;
        if (idx >= cnt) idx = cnt - 1;
        ids[tid] = list[idx];
    }
    __syncthreads();

    const int c0 = wave * CCH;
    const float* Wk = Ww + (size_t)k * D * D + c0;

    float acc[2][CCH];
    #pragma unroll
    for (int s = 0; s < 2; ++s)
        #pragma unroll
        for (int cc = 0; cc < CCH; ++cc) acc[s][cc] = 0.0f;
    float bp[2] = {0.0f, 0.0f};

    const int qj = tid & 15;             // float4 slot within 64-float row half
    const int rb = tid >> 4;             // row 0..31 per sweep

    for (int p = 0; p < 2; ++p) {
        if (p) __syncthreads();          // previous pass's readers done
        // stage 128 rows x 64 floats, float4 (16 consecutive lanes = 256 B row)
        #pragma unroll
        for (int sw = 0; sw < 4; ++sw) {
            const int r = sw * 32 + rb;
            const int id = ids[r];
            const float4 v = *(const float4*)&x[(size_t)id * D + p * JH + qj * 4];
            xT[qj * 4 + 0][r] = v.x;
            xT[qj * 4 + 1][r] = v.y;
            xT[qj * 4 + 2][r] = v.z;
            xT[qj * 4 + 3][r] = v.w;
        }
        __syncthreads();

        #pragma unroll 2
        for (int jl = 0; jl < JH; ++jl) {
            const float* wr = Wk + (p * JH + jl) * D;  // wave-uniform s_load
            const float xv0 = xT[jl][lane];
            const float xv1 = xT[jl][lane + 64];
            #pragma unroll
            for (int cc = 0; cc < CCH; ++cc) {
                const float wv = wr[cc];
                acc[0][cc] = fmaf(xv0, wv, acc[0][cc]);
                acc[1][cc] = fmaf(xv1, wv, acc[1][cc]);
            }
        }

        // base partial: this wave's j-columns [c0,c0+16) live in pass c0/64
        if ((c0 >> 6) == p) {
            const int jb = c0 & (JH - 1);
            #pragma unroll
            for (int cc = 0; cc < CCH; ++cc) {
                const float wm = Wm[k * D + c0 + cc];
                bp[0] = fmaf(xT[jb + cc][lane], wm, bp[0]);
                bp[1] = fmaf(xT[jb + cc][lane + 64], wm, bp[1]);
            }
        }
    }

    // t partial (relu then dot with Wm over this wave's columns)
    float tp[2] = {0.0f, 0.0f};
    #pragma unroll
    for (int cc = 0; cc < CCH; ++cc) {
        const float wm = Wm[k * D + c0 + cc];
        tp[0] = fmaf(fmaxf(acc[0][cc], 0.0f), wm, tp[0]);
        tp[1] = fmaf(fmaxf(acc[1][cc], 0.0f), wm, tp[1]);
    }
    __syncthreads();                     // last pass readers done before red
    redT[wave][lane]      = tp[0];
    redT[wave][lane + 64] = tp[1];
    redB[wave][lane]      = bp[0];
    redB[wave][lane + 64] = bp[1];
    __syncthreads();

    if (wave < 2) {
        const int r = wave * 64 + lane;          // node-slot 0..127
        const int idx = nbase + r;
        if (idx < cnt) {
            const int id = ids[r];
            float ts = 0.0f, bs = 0.0f;
            #pragma unroll
            for (int wv = 0; wv < GWAVES; ++wv) {
                ts += redT[wv][r];
                bs += redB[wv][r];
            }
            t32[(size_t)id * K + k]    = ts;
            base32[(size_t)id * K + k] = bs;
        }
    }
}

// ---------------------------------------------------------------------------
// Phase 2 (fp32): agg32[dst,k] += t32[src,k]. Lane = (edge, head): 8-lane
// groups cover one edge's 8 heads -> atomics merge into one 32 B sector
// (R5 WRITE_SIZE evidence). Gated by mb[dst]&mb[src] bits: t32 is read (and
// defined) only where src is masked; agg is dead where dst unmasked. This
// removes the need to zero t32 at all.
// ---------------------------------------------------------------------------
__global__ __launch_bounds__(256)
void scatter_kernel(const int* __restrict__ ei,
                    const unsigned char* __restrict__ mb,
                    const float* __restrict__ t32,
                    float* __restrict__ agg32)
{
    const long long tid = (long long)blockIdx.x * 256 + threadIdx.x;
    if (tid >= (long long)N_EDGES * K) return;
    const int k = (int)(tid & (K - 1));
    const long long e = tid >> 3;
    const int d = ei[(long long)N_EDGES + e];   // broadcast within 8-lane group
    const int s = ei[e];
    const unsigned md = mb[d] & mb[s];
    if (!((md >> k) & 1)) return;
    const float v = t32[(size_t)s * K + k];     // defined: src masked
    if (v != 0.0f) atomicAdd(&agg32[(size_t)d * K + k], v);
}

// ---------------------------------------------------------------------------
// Phase 3: tentative combine + flag near-zero scores for exact repair.
// Also zeroes s64 for flagged entries (replaces the 6.4 MB s64 memset).
// head bool = (mask>0) && (score>0); output = first <=2 true heads (lax.top_k
// on all-equal norms tie-breaks by lowest index).
// ---------------------------------------------------------------------------
__global__ __launch_bounds__(256)
void combine_flag_kernel(const unsigned char* __restrict__ mb,
                         const float* __restrict__ base32,
                         const float* __restrict__ agg32,
                         float* __restrict__ out,
                         unsigned char* __restrict__ flag8,
                         double* __restrict__ s64)
{
    const int n = blockIdx.x * 256 + threadIdx.x;
    if (n >= N_NODES) return;
    const unsigned m8 = mb[n];
    float o[K];
    int cnt = 0, fl = 0;
    #pragma unroll
    for (int k = 0; k < K; ++k) {
        const float s = base32[(size_t)n * K + k] + agg32[(size_t)n * K + k];
        const bool masked = (m8 >> k) & 1;
        const bool hm = masked && (s > 0.0f);
        if (masked && fabsf(s) < TAU) fl |= (1 << k);
        o[k] = (hm && cnt < 2) ? 1.0f : 0.0f;
        cnt += hm ? 1 : 0;
    }
    float4* op = (float4*)(out + (size_t)n * K);
    op[0] = make_float4(o[0], o[1], o[2], o[3]);
    op[1] = make_float4(o[4], o[5], o[6], o[7]);
    flag8[n] = (unsigned char)fl;
    if (fl) {
        #pragma unroll
        for (int k = 0; k < K; ++k)
            if ((fl >> k) & 1) s64[(size_t)n * K + k] = 0.0;
    }
}

// ---------------------------------------------------------------------------
// Repair A: edges into flagged (dst,k) with masked src -> worklist.
// ---------------------------------------------------------------------------
__global__ __launch_bounds__(256)
void edge_flag_kernel(const int* __restrict__ ei,
                      const unsigned char* __restrict__ mb,
                      const unsigned char* __restrict__ flag8,
                      int2* __restrict__ wl,
                      int* __restrict__ wlcnt)
{
    const int e = blockIdx.x * 256 + threadIdx.x;
    if (e >= N_EDGES) return;
    const int d = ei[(long long)N_EDGES + e];
    unsigned f = flag8[d];
    if (!f) return;
    const int s = ei[e];
    f &= mb[s];
    while (f) {
        const int k = __ffs(f) - 1;
        f &= f - 1;
        const int idx = atomicAdd(wlcnt, 1);
        if (idx < WL_CAP) wl[idx] = make_int2(s | (k << 20), d);
    }
}

// ---------------------------------------------------------------------------
// Repair B: one wave per worklist entry: exact fp64 t, atomic into score64.
// ---------------------------------------------------------------------------
__global__ __launch_bounds__(256)
void repair_t_kernel(const float* __restrict__ x,
                     const float* __restrict__ Ww,
                     const float* __restrict__ Wm,
                     const int2* __restrict__ wl,
                     const int* __restrict__ wlcnt,
                     double* __restrict__ score64)
{
    const int lane = threadIdx.x & 63;
    const int waveId = blockIdx.x * 4 + (threadIdx.x >> 6);
    const int nWaves = gridDim.x * 4;
    int cnt = *wlcnt;
    if (cnt > WL_CAP) cnt = WL_CAP;
    for (int w = waveId; w < cnt; w += nWaves) {
        const int2 ent = wl[w];
        const int s = __builtin_amdgcn_readfirstlane(ent.x & 0xFFFFF);
        const int k = __builtin_amdgcn_readfirstlane(ent.x >> 20);
        const int d = ent.y;
        const float* xr = x + (size_t)s * D;
        const float* Wk = Ww + (size_t)k * D * D;
        double c0 = 0.0, c1 = 0.0;
        for (int j = 0; j < D; ++j) {
            const double xd = (double)xr[j];
            c0 = fma(xd, (double)Wk[j * D + lane], c0);
            c1 = fma(xd, (double)Wk[j * D + lane + 64], c1);
        }
        double ts = fmax(c0, 0.0) * (double)Wm[k * D + lane]
                  + fmax(c1, 0.0) * (double)Wm[k * D + lane + 64];
        #pragma unroll
        for (int off = 32; off > 0; off >>= 1) ts += __shfl_xor(ts, off);
        if (lane == 0) atomicAdd(&score64[(size_t)d * K + k], ts);
    }
}

// ---------------------------------------------------------------------------
// Repair C: rewrite output rows of flagged nodes using exact scores.
// ---------------------------------------------------------------------------
__global__ __launch_bounds__(256)
void repair_combine_kernel(const float* __restrict__ x,
                           const unsigned char* __restrict__ mb,
                           const float* __restrict__ Wm,
                           const float* __restrict__ base32,
                           const float* __restrict__ agg32,
                           const double* __restrict__ score64,
                           const unsigned char* __restrict__ flag8,
                           float* __restrict__ out)
{
    const int n = blockIdx.x * 256 + threadIdx.x;
    if (n >= N_NODES) return;
    const unsigned f = flag8[n];
    if (!f) return;
    const unsigned m8 = mb[n];
    float o[K];
    int cnt = 0;
    #pragma unroll
    for (int k = 0; k < K; ++k) {
        bool hm;
        if ((f >> k) & 1) {
            double b = 0.0;
            for (int j = 0; j < D; ++j)
                b = fma((double)x[(size_t)n * D + j], (double)Wm[k * D + j], b);
            hm = (b + score64[(size_t)n * K + k]) > 0.0;
        } else {
            hm = ((m8 >> k) & 1) &&
                 ((base32[(size_t)n * K + k] + agg32[(size_t)n * K + k]) > 0.0f);
        }
        o[k] = (hm && cnt < 2) ? 1.0f : 0.0f;
        cnt += hm ? 1 : 0;
    }
    float4* op = (float4*)(out + (size_t)n * K);
    op[0] = make_float4(o[0], o[1], o[2], o[3]);
    op[1] = make_float4(o[4], o[5], o[6], o[7]);
}

extern "C" void kernel_launch(void* const* d_in, const int* in_sizes, int n_in,
                              void* d_out, int out_size, void* d_ws, size_t ws_size,
                              hipStream_t stream)
{
    const float* x    = (const float*)d_in[0];
    const int*   ei   = (const int*)d_in[1];   // edge_index [2, E] int32
    const float* mask = (const float*)d_in[2]; // [N, K]
    const float* Ww   = (const float*)d_in[3]; // [K, D, D]
    const float* Wm   = (const float*)d_in[4]; // [K, D, 1]
    float* out = (float*)d_out;                // [N, K] float32

    // workspace layout:
    //   [0, 3.2M)            t32      f32[N*K]   (no memset needed: gated reads)
    //   [3.2M, 6.4M)         agg32    f32[N*K]
    //   [6.4M, 12.8M)        s64      f64[N*K]  (early: lists int[K][N], 3.2M;
    //                                  flagged entries zeroed by combine_flag)
    //   [12.8M, +100000)     flag8    u8[N]     (fully written by combine_flag)
    //   [12,900,000, +32)    cnts     int[8]
    //   [12,900,032, +4+pad) wlcnt    int
    //   [12,900,040, +2M)    wl       int2[WL_CAP]
    //   [14,997,192, +3.2M)  base32   f32[N*K]
    //   [18,197,192, +100000) mb      u8[N]      (end ~18.3 MB)
    char* w = (char*)d_ws;
    float*         t32    = (float*)w;
    float*         agg32  = (float*)(w + 3200000);
    double*        s64    = (double*)(w + 6400000);
    int*           lists  = (int*)(w + 6400000);       // overlays s64 (dead then)
    unsigned char* flag8  = (unsigned char*)(w + 12800000);
    int*           cnts   = (int*)(w + 12900000);
    int*           wlcnt  = (int*)(w + 12900032);
    int2*          wl     = (int2*)(w + 12900040);
    float*         b32    = (float*)(w + 12900040 + (size_t)WL_CAP * 8);
    unsigned char* mb     = (unsigned char*)(w + 12900040 + (size_t)WL_CAP * 8 + 3200000);

    // zero agg32 (accumulator) and cnts|wlcnt only
    hipMemsetAsync(agg32, 0, 3200000, stream);
    hipMemsetAsync(w + 12900000, 0, 64, stream);

    compact_kernel<<<(N_NODES + 255) / 256, 256, 0, stream>>>(mask, lists, cnts, mb);

    // grid: chunks padded to x8 so bid = c0*64 + h*8 + clo covers all (c,h)
    const int nchunks = (N_NODES + CHUNK - 1) / CHUNK;          // 782
    const int nc8 = (nchunks + 7) & ~7;                          // 784
    head_gemm_kernel<<<nc8 * K, 512, 0, stream>>>(x, Ww, Wm, lists, cnts, t32, b32);

    const long long nek = (long long)N_EDGES * K;
    scatter_kernel<<<(int)((nek + 255) / 256), 256, 0, stream>>>(ei, mb, t32, agg32);

    combine_flag_kernel<<<(N_NODES + 255) / 256, 256, 0, stream>>>(
        mb, b32, agg32, out, flag8, s64);

    edge_flag_kernel<<<(N_EDGES + 255) / 256, 256, 0, stream>>>(
        ei, mb, flag8, wl, wlcnt);

    repair_t_kernel<<<512, 256, 0, stream>>>(x, Ww, Wm, wl, wlcnt, s64);

    repair_combine_kernel<<<(N_NODES + 255) / 256, 256, 0, stream>>>(
        x, mb, Wm, b32, agg32, s64, flag8, out);
}